// Round 1
// baseline (5703.905 us; speedup 1.0000x reference)
//
#include <hip/hip_runtime.h>
#include <hip/hip_fp16.h>

#define NDIM 92
#define HDIM 64
#define EDIM 41
#define ZC   128   // 2H
#define CIN  169   // 2H + EDIM
#define NB   2048  // pass-A grid / stats partial rows

// ---------------------------------------------------------------- embedding
// h[n][j] = sum_k nf[n][k] * W[k][j] + b[j]
__global__ __launch_bounds__(256) void k_embed(
    const float* __restrict__ nf, const float* __restrict__ W,
    const float* __restrict__ b, float* __restrict__ h, int N)
{
    __shared__ float Wl[NDIM * HDIM];
    __shared__ float nfl[4][NDIM];
    int t = threadIdx.x;
    for (int i = t; i < NDIM * HDIM; i += 256) Wl[i] = W[i];
    int n0 = blockIdx.x * 4;
    for (int i = t; i < 4 * NDIM; i += 256) {
        int slot = i / NDIM, k = i - slot * NDIM;
        int n = n0 + slot;
        nfl[slot][k] = (n < N) ? nf[n * NDIM + k] : 0.f;
    }
    __syncthreads();
    int j = t & 63, slot = t >> 6;
    int n = n0 + slot;
    if (n >= N) return;
    float acc = b[j];
    #pragma unroll
    for (int k = 0; k < NDIM; k++) acc += nfl[slot][k] * Wl[k * HDIM + j];
    h[n * HDIM + j] = acc;
}

// ---------------------------------------------------------------- node GEMM
// PQ[n][c] = sum_k h[n][k] * Wcat[k][c], c in [0,256)
// Wcat[k][c] = c<128 ? convW[k][c] (src half) : convW[64+k][c-128] (dst half)
__global__ __launch_bounds__(256) void k_pq(
    const float* __restrict__ h, const float* __restrict__ Wl,
    float* __restrict__ PQ, int N)
{
    __shared__ float Wcat[64 * 256];
    __shared__ float hl[32 * 64];
    int t = threadIdx.x;
    for (int i = t; i < 64 * 256; i += 256) {
        int k = i >> 8, c = i & 255;
        Wcat[i] = (c < 128) ? Wl[k * 128 + c] : Wl[(64 + k) * 128 + (c - 128)];
    }
    int jg = t & 63, w = t >> 6;   // lane -> 4 consecutive cols; wave -> 8 nodes
    int ntiles = (N + 31) >> 5;
    for (int tile = blockIdx.x; tile < ntiles; tile += gridDim.x) {
        int nbase = tile << 5;
        __syncthreads();
        for (int i = t; i < 32 * 64; i += 256) {
            int nn = nbase + (i >> 6);
            hl[i] = (nn < N) ? h[nn * 64 + (i & 63)] : 0.f;
        }
        __syncthreads();
        float acc[8][4];
        #pragma unroll
        for (int n = 0; n < 8; n++)
            acc[n][0] = acc[n][1] = acc[n][2] = acc[n][3] = 0.f;
        for (int k = 0; k < 64; k++) {
            float4 w4 = *(const float4*)&Wcat[k * 256 + jg * 4];
            #pragma unroll
            for (int n = 0; n < 8; n++) {
                float hv = hl[(w * 8 + n) * 64 + k];
                acc[n][0] += hv * w4.x; acc[n][1] += hv * w4.y;
                acc[n][2] += hv * w4.z; acc[n][3] += hv * w4.w;
            }
        }
        #pragma unroll
        for (int n = 0; n < 8; n++) {
            int nn = nbase + w * 8 + n;
            if (nn < N)
                *(float4*)&PQ[nn * 256 + jg * 4] =
                    make_float4(acc[n][0], acc[n][1], acc[n][2], acc[n][3]);
        }
    }
}

// ---------------------------------------------------------------- pass A
// z[e][j] = PQ[src[e]][j] + PQ[dst[e]][128+j] + b[j] + sum_k ef[e][k]*Wbot[k][j]
// write z (fp16), accumulate per-column sum & sumsq partials per block.
__global__ __launch_bounds__(256) void k_passA(
    const float* __restrict__ PQ, const float* __restrict__ ef,
    const int* __restrict__ src, const int* __restrict__ dst,
    const float* __restrict__ Wl, const float* __restrict__ bias,
    __half* __restrict__ zh, float* __restrict__ partials, int E)
{
    __shared__ float Wb[EDIM * ZC];   // 21 KB
    int t = threadIdx.x;
    for (int i = t; i < EDIM * ZC; i += 256) {
        int k = i >> 7, j = i & 127;
        Wb[i] = Wl[(128 + k) * 128 + j];
    }
    __syncthreads();
    int j = t & 127, sub = t >> 7;    // 2 edges in flight per block-iter
    float bj = bias[j];
    float psum = 0.f, psq = 0.f;
    for (int e = blockIdx.x * 2 + sub; e < E; e += gridDim.x * 2) {
        int s = src[e], d = dst[e];
        float acc0 = PQ[s * 256 + j] + bj;
        float acc1 = PQ[d * 256 + 128 + j];
        const float* efe = ef + e * EDIM;
        #pragma unroll
        for (int k = 0; k < 40; k += 2) {
            acc0 += efe[k]     * Wb[k * 128 + j];
            acc1 += efe[k + 1] * Wb[(k + 1) * 128 + j];
        }
        acc0 += efe[40] * Wb[40 * 128 + j];
        float z = acc0 + acc1;
        zh[e * 128 + j] = __float2half(z);
        psum += z; psq += z * z;
    }
    __shared__ float red[512];
    red[t] = psum; red[256 + t] = psq;
    __syncthreads();
    if (t < 128) {
        partials[blockIdx.x * 256 + t]       = red[t] + red[t + 128];
        partials[blockIdx.x * 256 + 128 + t] = red[256 + t] + red[256 + t + 128];
    }
}

// ---------------------------------------------------------------- stats
__global__ __launch_bounds__(256) void k_red1(
    const float* __restrict__ partials, float* __restrict__ p2, int nb)
{
    int t = threadIdx.x, r = blockIdx.x;
    float s = 0.f;
    int b0 = r * 32, b1 = b0 + 32; if (b1 > nb) b1 = nb;
    for (int b = b0; b < b1; b++) s += partials[b * 256 + t];
    p2[r * 256 + t] = s;
}

__global__ __launch_bounds__(256) void k_bnstats(
    const float* __restrict__ p2, const float* __restrict__ gamma,
    const float* __restrict__ beta, float* __restrict__ bnA,
    float* __restrict__ bnC, int R, float invE)
{
    int t = threadIdx.x;
    float s = 0.f;
    for (int r = 0; r < R; r++) s += p2[r * 256 + t];
    __shared__ float red[256];
    red[t] = s;
    __syncthreads();
    if (t < 128) {
        float mean = red[t] * invE;
        float var  = red[128 + t] * invE - mean * mean;
        float a = gamma[t] * rsqrtf(var + 1e-5f);
        bnA[t] = a;
        bnC[t] = beta[t] - mean * a;
    }
}

// ---------------------------------------------------------------- pass B
// msg = sigmoid(zn[:, :64]) * softplus(zn[:, 64:]); h[src] += msg (atomics)
__global__ __launch_bounds__(256) void k_passB(
    const __half* __restrict__ zh, const int* __restrict__ src,
    const float* __restrict__ bnA, const float* __restrict__ bnC,
    float* __restrict__ h, int E)
{
    int t = threadIdx.x;
    int j = t & 63, slot = t >> 6;
    float a0 = bnA[j],      c0 = bnC[j];
    float a1 = bnA[64 + j], c1 = bnC[64 + j];
    for (int e = blockIdx.x * 4 + slot; e < E; e += gridDim.x * 4) {
        float za = __half2float(zh[e * 128 + j])      * a0 + c0;
        float zb = __half2float(zh[e * 128 + 64 + j]) * a1 + c1;
        float sig = 1.f / (1.f + __expf(-za));
        float sp  = fmaxf(zb, 0.f) + log1pf(__expf(-fabsf(zb)));
        atomicAdd(&h[src[e] * 64 + j], sig * sp);
    }
}

// ---------------------------------------------------------------- pooling
__global__ __launch_bounds__(256) void k_pool(
    const float* __restrict__ h, const int* __restrict__ gid,
    float* __restrict__ pool, float* __restrict__ cnt, int N)
{
    int t = threadIdx.x;
    int j = t & 63, slot = t >> 6;
    int n = blockIdx.x * 4 + slot;
    if (n >= N) return;
    int g = gid[n];
    atomicAdd(&pool[g * 64 + j], h[n * 64 + j]);
    if (j == 0) atomicAdd(&cnt[g], 1.f);
}

// ---------------------------------------------------------------- head
__global__ __launch_bounds__(128) void k_head(
    const float* __restrict__ pool, const float* __restrict__ cnt,
    const float* __restrict__ fcW, const float* __restrict__ fcb,
    const float* __restrict__ outW, const float* __restrict__ outb,
    float* __restrict__ out, int G)
{
    int g = blockIdx.x, t = threadIdx.x;
    __shared__ float pl[64];
    if (t < 64) pl[t] = pool[g * 64 + t] / fmaxf(cnt[g], 1.f);
    __syncthreads();
    float acc = fcb[t];
    #pragma unroll
    for (int k = 0; k < 64; k++) acc += pl[k] * fcW[k * 128 + t];
    float sp = fmaxf(acc, 0.f) + log1pf(__expf(-fabsf(acc)));
    float v = sp * outW[t];
    __shared__ float red[128];
    red[t] = v;
    __syncthreads();
    for (int s = 64; s > 0; s >>= 1) {
        if (t < s) red[t] += red[t + s];
        __syncthreads();
    }
    if (t == 0) out[g] = red[0] + outb[0];
}

// ---------------------------------------------------------------- launcher
extern "C" void kernel_launch(void* const* d_in, const int* in_sizes, int n_in,
                              void* d_out, int out_size, void* d_ws, size_t ws_size,
                              hipStream_t stream)
{
    const float* nf    = (const float*)d_in[0];
    const int*   ei    = (const int*)d_in[1];
    const float* ef    = (const float*)d_in[2];
    const int*   gid   = (const int*)d_in[3];
    const float* embW  = (const float*)d_in[4];
    const float* embB  = (const float*)d_in[5];
    const float* convW = (const float*)d_in[6];
    const float* convB = (const float*)d_in[7];
    const float* gam   = (const float*)d_in[8];
    const float* bet   = (const float*)d_in[9];
    const float* fcW   = (const float*)d_in[10];
    const float* fcb   = (const float*)d_in[11];
    const float* outW  = (const float*)d_in[12];
    const float* outb  = (const float*)d_in[13];
    float* out = (float*)d_out;

    int N = in_sizes[0] / NDIM;
    int E = in_sizes[1] / 2;
    int G = out_size;
    const int* src = ei;
    const int* dst = ei + E;

    char* ws = (char*)d_ws;
    size_t off = 0;
    auto alloc = [&](size_t bytes) {
        void* p = ws + off;
        off = (off + bytes + 255) & ~(size_t)255;
        return p;
    };
    float*  h        = (float*)alloc((size_t)N * 64 * 4);
    float*  PQ       = (float*)alloc((size_t)N * 256 * 4);
    __half* zh       = (__half*)alloc((size_t)E * 128 * 2);
    float*  partials = (float*)alloc((size_t)NB * 256 * 4);
    float*  p2       = (float*)alloc((size_t)64 * 256 * 4);
    float*  bnA      = (float*)alloc(128 * 4);
    float*  bnC      = (float*)alloc(128 * 4);
    float*  pool     = (float*)alloc((size_t)G * 65 * 4);  // sums + counts
    float*  cnt      = pool + (size_t)G * 64;

    k_embed<<<(N + 3) / 4, 256, 0, stream>>>(nf, embW, embB, h, N);

    for (int l = 0; l < 3; l++) {
        const float* Wl = convW + (size_t)l * CIN * ZC;
        k_pq<<<1024, 256, 0, stream>>>(h, Wl, PQ, N);
        k_passA<<<NB, 256, 0, stream>>>(PQ, ef, src, dst, Wl, convB + l * ZC,
                                        zh, partials, E);
        k_red1<<<64, 256, 0, stream>>>(partials, p2, NB);
        k_bnstats<<<1, 256, 0, stream>>>(p2, gam + l * ZC, bet + l * ZC,
                                         bnA, bnC, 64, 1.f / (float)E);
        k_passB<<<4096, 256, 0, stream>>>(zh, src, bnA, bnC, h, E);
    }

    hipMemsetAsync(pool, 0, (size_t)G * 65 * 4, stream);
    k_pool<<<(N + 3) / 4, 256, 0, stream>>>(h, gid, pool, cnt, N);
    k_head<<<G, 128, 0, stream>>>(pool, cnt, fcW, fcb, outW, outb, out, G);
}

// Round 2
// 4320.981 us; speedup vs baseline: 1.3200x; 1.3200x over previous
//
#include <hip/hip_runtime.h>
#include <hip/hip_fp16.h>

#define NDIM 92
#define HDIM 64
#define EDIM 41
#define ZC   128   // 2H
#define CIN  169   // 2H + EDIM
#define NB   2048  // pass-A grid / stats partial rows

// ---------------------------------------------------------------- embedding
// h[n][j] = sum_k nf[n][k] * W[k][j] + b[j]
__global__ __launch_bounds__(256) void k_embed(
    const float* __restrict__ nf, const float* __restrict__ W,
    const float* __restrict__ b, float* __restrict__ h, int N)
{
    __shared__ float Wl[NDIM * HDIM];
    __shared__ float nfl[4][NDIM];
    int t = threadIdx.x;
    for (int i = t; i < NDIM * HDIM; i += 256) Wl[i] = W[i];
    int n0 = blockIdx.x * 4;
    for (int i = t; i < 4 * NDIM; i += 256) {
        int slot = i / NDIM, k = i - slot * NDIM;
        int n = n0 + slot;
        nfl[slot][k] = (n < N) ? nf[n * NDIM + k] : 0.f;
    }
    __syncthreads();
    int j = t & 63, slot = t >> 6;
    int n = n0 + slot;
    if (n >= N) return;
    float acc = b[j];
    #pragma unroll
    for (int k = 0; k < NDIM; k++) acc += nfl[slot][k] * Wl[k * HDIM + j];
    h[n * HDIM + j] = acc;
}

// ---------------------------------------------------------------- node GEMM
// PQ[n][c] = sum_k h[n][k] * Wcat[k][c], c in [0,256)
// Wcat[k][c] = c<128 ? convW[k][c] (src half) : convW[64+k][c-128] (dst half)
__global__ __launch_bounds__(256) void k_pq(
    const float* __restrict__ h, const float* __restrict__ Wl,
    float* __restrict__ PQ, int N)
{
    __shared__ float Wcat[64 * 256];
    __shared__ float hl[32 * 64];
    int t = threadIdx.x;
    for (int i = t; i < 64 * 256; i += 256) {
        int k = i >> 8, c = i & 255;
        Wcat[i] = (c < 128) ? Wl[k * 128 + c] : Wl[(64 + k) * 128 + (c - 128)];
    }
    int jg = t & 63, w = t >> 6;   // lane -> 4 consecutive cols; wave -> 8 nodes
    int ntiles = (N + 31) >> 5;
    for (int tile = blockIdx.x; tile < ntiles; tile += gridDim.x) {
        int nbase = tile << 5;
        __syncthreads();
        for (int i = t; i < 32 * 64; i += 256) {
            int nn = nbase + (i >> 6);
            hl[i] = (nn < N) ? h[nn * 64 + (i & 63)] : 0.f;
        }
        __syncthreads();
        float acc[8][4];
        #pragma unroll
        for (int n = 0; n < 8; n++)
            acc[n][0] = acc[n][1] = acc[n][2] = acc[n][3] = 0.f;
        for (int k = 0; k < 64; k++) {
            float4 w4 = *(const float4*)&Wcat[k * 256 + jg * 4];
            #pragma unroll
            for (int n = 0; n < 8; n++) {
                float hv = hl[(w * 8 + n) * 64 + k];
                acc[n][0] += hv * w4.x; acc[n][1] += hv * w4.y;
                acc[n][2] += hv * w4.z; acc[n][3] += hv * w4.w;
            }
        }
        #pragma unroll
        for (int n = 0; n < 8; n++) {
            int nn = nbase + w * 8 + n;
            if (nn < N)
                *(float4*)&PQ[nn * 256 + jg * 4] =
                    make_float4(acc[n][0], acc[n][1], acc[n][2], acc[n][3]);
        }
    }
}

// ---------------------------------------------------------------- pass A  (v2)
// z[e][j] = PQ[src[e]][j] + PQ[dst[e]][128+j] + b[j] + sum_k ef[e][k]*Wbot[k][j]
// One edge per wave-pair slot: edge id is wave-uniform (readfirstlane) so
// ef[e][*] / src[e] / dst[e] become SMEM scalar loads; Wbot column lives in
// 41 VGPRs per thread (no per-edge LDS traffic at all).
__global__ __launch_bounds__(256) void k_passA(
    const float* __restrict__ PQ, const float* __restrict__ ef,
    const int* __restrict__ src, const int* __restrict__ dst,
    const float* __restrict__ Wl, const float* __restrict__ bias,
    __half* __restrict__ zh, float* __restrict__ partials, int E)
{
    int t = threadIdx.x;
    int lane = t & 63;
    int waveid = __builtin_amdgcn_readfirstlane(t >> 6);  // 0..3, SGPR
    int pair = waveid >> 1;                 // edge slot 0/1 within block
    int jcol = ((waveid & 1) << 6) | lane;  // column 0..127 (col(t) == t&127)

    // Wbot column -> registers (once per block lifetime)
    float wreg[EDIM];
    #pragma unroll
    for (int k = 0; k < EDIM; k++) wreg[k] = Wl[(128 + k) * 128 + jcol];
    float bj = bias[jcol];

    float psum = 0.f, psq = 0.f;
    int estep = gridDim.x * 2;
    for (int e = blockIdx.x * 2 + pair; e < E; e += estep) {
        int s = src[e], d = dst[e];                   // scalar loads (e uniform)
        const float* efe = ef + (size_t)e * EDIM;     // scalar base -> s_load
        float acc0 = PQ[(size_t)s * 256 + jcol];
        float acc1 = PQ[(size_t)d * 256 + 128 + jcol] + bj;
        #pragma unroll
        for (int k = 0; k < 40; k += 2) {
            acc0 += efe[k]     * wreg[k];
            acc1 += efe[k + 1] * wreg[k + 1];
        }
        acc0 += efe[40] * wreg[40];
        float z = acc0 + acc1;
        zh[(size_t)e * 128 + jcol] = __float2half(z);
        psum += z; psq += z * z;
    }
    __shared__ float red[512];
    red[t] = psum; red[256 + t] = psq;
    __syncthreads();
    if (t < 128) {
        partials[blockIdx.x * 256 + t]       = red[t] + red[t + 128];
        partials[blockIdx.x * 256 + 128 + t] = red[256 + t] + red[256 + t + 128];
    }
}

// ---------------------------------------------------------------- stats
__global__ __launch_bounds__(256) void k_red1(
    const float* __restrict__ partials, float* __restrict__ p2, int nb)
{
    int t = threadIdx.x, r = blockIdx.x;
    float s = 0.f;
    int b0 = r * 32, b1 = b0 + 32; if (b1 > nb) b1 = nb;
    for (int b = b0; b < b1; b++) s += partials[b * 256 + t];
    p2[r * 256 + t] = s;
}

__global__ __launch_bounds__(256) void k_bnstats(
    const float* __restrict__ p2, const float* __restrict__ gamma,
    const float* __restrict__ beta, float* __restrict__ bnA,
    float* __restrict__ bnC, int R, float invE)
{
    int t = threadIdx.x;
    float s = 0.f;
    for (int r = 0; r < R; r++) s += p2[r * 256 + t];
    __shared__ float red[256];
    red[t] = s;
    __syncthreads();
    if (t < 128) {
        float mean = red[t] * invE;
        float var  = red[128 + t] * invE - mean * mean;
        float a = gamma[t] * rsqrtf(var + 1e-5f);
        bnA[t] = a;
        bnC[t] = beta[t] - mean * a;
    }
}

// ---------------------------------------------------------------- pass B
// msg = sigmoid(zn[:, :64]) * softplus(zn[:, 64:]); h[src] += msg (atomics)
__global__ __launch_bounds__(256) void k_passB(
    const __half* __restrict__ zh, const int* __restrict__ src,
    const float* __restrict__ bnA, const float* __restrict__ bnC,
    float* __restrict__ h, int E)
{
    int t = threadIdx.x;
    int j = t & 63, slot = t >> 6;
    float a0 = bnA[j],      c0 = bnC[j];
    float a1 = bnA[64 + j], c1 = bnC[64 + j];
    for (int e = blockIdx.x * 4 + slot; e < E; e += gridDim.x * 4) {
        float za = __half2float(zh[e * 128 + j])      * a0 + c0;
        float zb = __half2float(zh[e * 128 + 64 + j]) * a1 + c1;
        float sig = 1.f / (1.f + __expf(-za));
        float sp  = fmaxf(zb, 0.f) + log1pf(__expf(-fabsf(zb)));
        atomicAdd(&h[src[e] * 64 + j], sig * sp);
    }
}

// ---------------------------------------------------------------- pooling
__global__ __launch_bounds__(256) void k_pool(
    const float* __restrict__ h, const int* __restrict__ gid,
    float* __restrict__ pool, float* __restrict__ cnt, int N)
{
    int t = threadIdx.x;
    int j = t & 63, slot = t >> 6;
    int n = blockIdx.x * 4 + slot;
    if (n >= N) return;
    int g = gid[n];
    atomicAdd(&pool[g * 64 + j], h[n * 64 + j]);
    if (j == 0) atomicAdd(&cnt[g], 1.f);
}

// ---------------------------------------------------------------- head
__global__ __launch_bounds__(128) void k_head(
    const float* __restrict__ pool, const float* __restrict__ cnt,
    const float* __restrict__ fcW, const float* __restrict__ fcb,
    const float* __restrict__ outW, const float* __restrict__ outb,
    float* __restrict__ out, int G)
{
    int g = blockIdx.x, t = threadIdx.x;
    __shared__ float pl[64];
    if (t < 64) pl[t] = pool[g * 64 + t] / fmaxf(cnt[g], 1.f);
    __syncthreads();
    float acc = fcb[t];
    #pragma unroll
    for (int k = 0; k < 64; k++) acc += pl[k] * fcW[k * 128 + t];
    float sp = fmaxf(acc, 0.f) + log1pf(__expf(-fabsf(acc)));
    float v = sp * outW[t];
    __shared__ float red[128];
    red[t] = v;
    __syncthreads();
    for (int s = 64; s > 0; s >>= 1) {
        if (t < s) red[t] += red[t + s];
        __syncthreads();
    }
    if (t == 0) out[g] = red[0] + outb[0];
}

// ---------------------------------------------------------------- launcher
extern "C" void kernel_launch(void* const* d_in, const int* in_sizes, int n_in,
                              void* d_out, int out_size, void* d_ws, size_t ws_size,
                              hipStream_t stream)
{
    const float* nf    = (const float*)d_in[0];
    const int*   ei    = (const int*)d_in[1];
    const float* ef    = (const float*)d_in[2];
    const int*   gid   = (const int*)d_in[3];
    const float* embW  = (const float*)d_in[4];
    const float* embB  = (const float*)d_in[5];
    const float* convW = (const float*)d_in[6];
    const float* convB = (const float*)d_in[7];
    const float* gam   = (const float*)d_in[8];
    const float* bet   = (const float*)d_in[9];
    const float* fcW   = (const float*)d_in[10];
    const float* fcb   = (const float*)d_in[11];
    const float* outW  = (const float*)d_in[12];
    const float* outb  = (const float*)d_in[13];
    float* out = (float*)d_out;

    int N = in_sizes[0] / NDIM;
    int E = in_sizes[1] / 2;
    int G = out_size;
    const int* src = ei;
    const int* dst = ei + E;

    char* ws = (char*)d_ws;
    size_t off = 0;
    auto alloc = [&](size_t bytes) {
        void* p = ws + off;
        off = (off + bytes + 255) & ~(size_t)255;
        return p;
    };
    float*  h        = (float*)alloc((size_t)N * 64 * 4);
    float*  PQ       = (float*)alloc((size_t)N * 256 * 4);
    __half* zh       = (__half*)alloc((size_t)E * 128 * 2);
    float*  partials = (float*)alloc((size_t)NB * 256 * 4);
    float*  p2       = (float*)alloc((size_t)64 * 256 * 4);
    float*  bnA      = (float*)alloc(128 * 4);
    float*  bnC      = (float*)alloc(128 * 4);
    float*  pool     = (float*)alloc((size_t)G * 65 * 4);  // sums + counts
    float*  cnt      = pool + (size_t)G * 64;

    k_embed<<<(N + 3) / 4, 256, 0, stream>>>(nf, embW, embB, h, N);

    for (int l = 0; l < 3; l++) {
        const float* Wl = convW + (size_t)l * CIN * ZC;
        k_pq<<<1024, 256, 0, stream>>>(h, Wl, PQ, N);
        k_passA<<<NB, 256, 0, stream>>>(PQ, ef, src, dst, Wl, convB + l * ZC,
                                        zh, partials, E);
        k_red1<<<64, 256, 0, stream>>>(partials, p2, NB);
        k_bnstats<<<1, 256, 0, stream>>>(p2, gam + l * ZC, bet + l * ZC,
                                         bnA, bnC, 64, 1.f / (float)E);
        k_passB<<<4096, 256, 0, stream>>>(zh, src, bnA, bnC, h, E);
    }

    hipMemsetAsync(pool, 0, (size_t)G * 65 * 4, stream);
    k_pool<<<(N + 3) / 4, 256, 0, stream>>>(h, gid, pool, cnt, N);
    k_head<<<G, 128, 0, stream>>>(pool, cnt, fcW, fcb, outW, outb, out, G);
}